// Round 2
// baseline (1139.753 us; speedup 1.0000x reference)
//
// Retry of round-0 kernel: previous bench died with "MI355X container failed
// twice" (broker/infra), no kernel-level signal. Code unchanged to preserve
// the baseline measurement.
#include <hip/hip_runtime.h>

#define BB 4
#define DE 128
#define DO_ 512
#define THW 10240
#define HW 1024
#define SCALE 0.08838834764831845f      // 1/sqrt(128)
#define INV2S2 0.05555555555555555f     // 1/(2*3^2)
#define NCH 32
#define CHT 320                          // 10240 / 32

// ws layout (float offsets)
#define WS_CENTERS 0                     // 2 * BB * THW        = 81920
#define WS_PART    81920                 // BB * NCH * HW * 2   = 262144
#define WS_STATS   344064                // BB * HW * 2         = 8192

// ---------------- init: zero mem part of out, copy q_out part ----------------
__global__ __launch_bounds__(256) void k_init(float* __restrict__ out,
                                              const float* __restrict__ qout)
{
    int idx = blockIdx.x * 256 + threadIdx.x;   // float4 slot, 4096*256 = 1048576 total
    int b  = idx >> 18;                          // 262144 float4 per batch
    int r  = idx & 262143;
    int c  = r >> 8;                             // 256 float4 per channel
    int q4 = r & 255;
    float4* dst = (float4*)out + idx;
    if (c < DO_) {
        *dst = make_float4(0.f, 0.f, 0.f, 0.f);
    } else {
        const float4* src = (const float4*)qout + ((size_t)(b * DO_ + (c - DO_)) << 8) + q4;
        *dst = *src;
    }
}

// ---------------- GEMM1: p[b][t][q] = sum_k mi[b][k][t] * qi[b][k][q] * SCALE ----------------
__global__ __launch_bounds__(256) void k_gemm1(const float* __restrict__ mi,
                                               const float* __restrict__ qi,
                                               float* __restrict__ p)
{
    __shared__ float As[DE][64];
    __shared__ float Bs[DE][64];
    int qb = blockIdx.x, tb = blockIdx.y, b = blockIdx.z;
    int tid = threadIdx.x;
    const float* A  = mi + (size_t)b * DE * THW + tb * 64;
    const float* Bq = qi + (size_t)b * DE * HW + qb * 64;
#pragma unroll
    for (int i = 0; i < 8; ++i) {
        int s = tid + i * 256;
        int k = s >> 4, c4 = (s & 15) << 2;
        *(float4*)&As[k][c4] = *(const float4*)&A[(size_t)k * THW + c4];
        *(float4*)&Bs[k][c4] = *(const float4*)&Bq[(size_t)k * HW + c4];
    }
    __syncthreads();
    int tx = tid & 15, ty = tid >> 4;
    float acc[4][4] = {};
#pragma unroll 8
    for (int k = 0; k < DE; ++k) {
        float4 a  = *(float4*)&As[k][ty << 2];
        float4 bq = *(float4*)&Bs[k][tx << 2];
        float av[4] = {a.x, a.y, a.z, a.w};
        float bv[4] = {bq.x, bq.y, bq.z, bq.w};
#pragma unroll
        for (int i = 0; i < 4; ++i)
#pragma unroll
            for (int j = 0; j < 4; ++j)
                acc[i][j] = fmaf(av[i], bv[j], acc[i][j]);
    }
    float* pp = p + ((size_t)b * THW + tb * 64 + (ty << 2)) * HW + qb * 64 + (tx << 2);
#pragma unroll
    for (int i = 0; i < 4; ++i) {
        float4 v = make_float4(acc[i][0] * SCALE, acc[i][1] * SCALE,
                               acc[i][2] * SCALE, acc[i][3] * SCALE);
        *(float4*)&pp[(size_t)i * HW] = v;
    }
}

// ---------------- argmax over q per (b,t) row; store gaussian center (cx, cy) ----------------
__global__ __launch_bounds__(256) void k_argmax(const float* __restrict__ p,
                                                float* __restrict__ centers)
{
    int row  = blockIdx.x * 4 + (threadIdx.x >> 6);   // b*THW + t, 40960 rows
    int lane = threadIdx.x & 63;
    const float4* pr = (const float4*)(p + (size_t)row * HW);
    float best = -3.4e38f; int bi = 0;
#pragma unroll
    for (int j = 0; j < 4; ++j) {
        float4 v = pr[j * 64 + lane];
        int base = j * 256 + lane * 4;
        if (v.x > best) { best = v.x; bi = base; }
        if (v.y > best) { best = v.y; bi = base + 1; }
        if (v.z > best) { best = v.z; bi = base + 2; }
        if (v.w > best) { best = v.w; bi = base + 3; }
    }
    for (int off = 1; off < 64; off <<= 1) {
        float ov = __shfl_xor(best, off);
        int   oi = __shfl_xor(bi, off);
        if (ov > best || (ov == best && oi < bi)) { best = ov; bi = oi; }
    }
    if (lane == 0) {
        centers[(size_t)row * 2]     = (float)(bi & 31);   // cx
        centers[(size_t)row * 2 + 1] = (float)(bi >> 5);   // cy
    }
}

// ---------------- online softmax stats over t (chunked): z = p - d2*INV2S2 ----------------
__global__ __launch_bounds__(256) void k_colstats(const float* __restrict__ p,
                                                  const float* __restrict__ centers,
                                                  float* __restrict__ part)
{
    int q  = blockIdx.x * 256 + threadIdx.x;
    int ch = blockIdx.y, b = blockIdx.z;
    float x = (float)(q & 31), y = (float)(q >> 5);
    const float* pp = p + ((size_t)b * THW + ch * CHT) * HW + q;
    const float2* ctr = (const float2*)centers + (size_t)b * THW + ch * CHT;
    float m = -3.0e38f, s = 0.f;
    for (int i = 0; i < CHT; ++i) {
        float2 c = ctr[i];
        float dx = x - c.x, dy = y - c.y;
        float z = pp[(size_t)i * HW] - (dx * dx + dy * dy) * INV2S2;
        float nm = fmaxf(m, z);
        s = s * __expf(m - nm) + __expf(z - nm);
        m = nm;
    }
    size_t o = ((size_t)(b * NCH + ch) * HW + q) * 2;
    part[o] = m; part[o + 1] = s;
}

// ---------------- combine chunk partials -> (M, 1/S) per (b,q) ----------------
__global__ __launch_bounds__(256) void k_reduce(const float* __restrict__ part,
                                                float* __restrict__ stats)
{
    int i = blockIdx.x * 256 + threadIdx.x;   // 0..4095 = b*HW + q
    int b = i >> 10, q = i & 1023;
    float M = -3.0e38f;
#pragma unroll
    for (int c = 0; c < NCH; ++c)
        M = fmaxf(M, part[((size_t)(b * NCH + c) * HW + q) * 2]);
    float S = 0.f;
#pragma unroll
    for (int c = 0; c < NCH; ++c) {
        size_t o = ((size_t)(b * NCH + c) * HW + q) * 2;
        S += part[o + 1] * __expf(part[o] - M);
    }
    stats[(size_t)i * 2] = M;
    stats[(size_t)i * 2 + 1] = 1.0f / S;
}

// ---------------- p_w = exp(p - d2*INV2S2 - M) * invS  (in place) ----------------
__global__ __launch_bounds__(256) void k_pw(float* __restrict__ p,
                                            const float* __restrict__ centers,
                                            const float* __restrict__ stats)
{
    int t = blockIdx.x, b = blockIdx.y;
    int tid = threadIdx.x;
    float2 c = ((const float2*)centers)[(size_t)b * THW + t];
    int q = tid << 2;
    float* pp = p + ((size_t)b * THW + t) * HW + q;
    float4 v = *(float4*)pp;
    const float* st = stats + ((size_t)b * HW + q) * 2;
    float4 s0 = *(const float4*)st;        // M0,I0,M1,I1
    float4 s1 = *(const float4*)(st + 4);  // M2,I2,M3,I3
    float y  = (float)(q >> 5);            // q..q+3 share the row (4 | q, 32 | row)
    float dy = y - c.y; float dy2 = dy * dy;
    float x0 = (float)(q & 31);
    float d0 = x0 - c.x, d1 = x0 + 1.f - c.x, d2 = x0 + 2.f - c.x, d3 = x0 + 3.f - c.x;
    v.x = __expf(v.x - (d0 * d0 + dy2) * INV2S2 - s0.x) * s0.y;
    v.y = __expf(v.y - (d1 * d1 + dy2) * INV2S2 - s0.z) * s0.w;
    v.z = __expf(v.z - (d2 * d2 + dy2) * INV2S2 - s1.x) * s1.y;
    v.w = __expf(v.w - (d3 * d3 + dy2) * INV2S2 - s1.z) * s1.w;
    *(float4*)pp = v;
}

// ---------------- GEMM2: mem[b][d][q] += sum_t mo[b][d][t] * pw[b][t][q] ----------------
// 64(M) x 128(N) tile, K split 4 ways via atomics; 256 threads, 4x8 per thread.
__global__ __launch_bounds__(256) void k_gemm2(const float* __restrict__ mo,
                                               const float* __restrict__ pw,
                                               float* __restrict__ out)
{
    __shared__ float As[16][68];    // transposed A, padded (+4) to break bank alignment
    __shared__ float Bs[16][128];
    int nb = blockIdx.x, mb = blockIdx.y;
    int b = blockIdx.z >> 2, ks = blockIdx.z & 3;
    int tid = threadIdx.x;
    int tx = tid & 15, ty = tid >> 4;
    const float* Ag = mo + (size_t)b * DO_ * THW + (size_t)(mb * 64) * THW + ks * 2560;
    const float* Bg = pw + ((size_t)b * THW + ks * 2560) * HW + nb * 128;
    int ai = tid >> 2, ak = (tid & 3) << 2;
    int bk = tid >> 5, bj = (tid & 31) << 2;
    float acc[4][8] = {};
    float4 a  = *(const float4*)&Ag[(size_t)ai * THW + ak];
    float4 b0 = *(const float4*)&Bg[(size_t)bk * HW + bj];
    float4 b1 = *(const float4*)&Bg[(size_t)(bk + 8) * HW + bj];
    for (int kc = 0; kc < 160; ++kc) {
        __syncthreads();
        As[ak + 0][ai] = a.x; As[ak + 1][ai] = a.y;
        As[ak + 2][ai] = a.z; As[ak + 3][ai] = a.w;
        *(float4*)&Bs[bk][bj]     = b0;
        *(float4*)&Bs[bk + 8][bj] = b1;
        __syncthreads();
        if (kc < 159) {
            int k0 = (kc + 1) * 16;
            a  = *(const float4*)&Ag[(size_t)ai * THW + k0 + ak];
            b0 = *(const float4*)&Bg[(size_t)(k0 + bk) * HW + bj];
            b1 = *(const float4*)&Bg[(size_t)(k0 + bk + 8) * HW + bj];
        }
#pragma unroll
        for (int k = 0; k < 16; ++k) {
            float4 av  = *(float4*)&As[k][ty << 2];
            float4 bv0 = *(float4*)&Bs[k][tx << 3];
            float4 bv1 = *(float4*)&Bs[k][(tx << 3) + 4];
            float aa[4]  = {av.x, av.y, av.z, av.w};
            float bbv[8] = {bv0.x, bv0.y, bv0.z, bv0.w, bv1.x, bv1.y, bv1.z, bv1.w};
#pragma unroll
            for (int i = 0; i < 4; ++i)
#pragma unroll
                for (int j = 0; j < 8; ++j)
                    acc[i][j] = fmaf(aa[i], bbv[j], acc[i][j]);
        }
    }
    float* Cg = out + (size_t)b * (2 * DO_ * HW)
                    + (size_t)(mb * 64 + (ty << 2)) * HW + nb * 128 + (tx << 3);
#pragma unroll
    for (int i = 0; i < 4; ++i)
#pragma unroll
        for (int j = 0; j < 8; ++j)
            atomicAdd(&Cg[(size_t)i * HW + j], acc[i][j]);
}

extern "C" void kernel_launch(void* const* d_in, const int* in_sizes, int n_in,
                              void* d_out, int out_size, void* d_ws, size_t ws_size,
                              hipStream_t stream)
{
    const float* m_in  = (const float*)d_in[0];
    const float* m_out = (const float*)d_in[1];
    const float* q_in  = (const float*)d_in[2];
    const float* q_out = (const float*)d_in[3];
    float* out = (float*)d_out;
    float* pw  = out + (size_t)BB * 2 * DO_ * HW;   // p / p_w region of d_out (in place)
    float* ws  = (float*)d_ws;
    float* centers = ws + WS_CENTERS;
    float* part    = ws + WS_PART;
    float* stats   = ws + WS_STATS;

    hipLaunchKernelGGL(k_init,    dim3(4096),        dim3(256), 0, stream, out, q_out);
    hipLaunchKernelGGL(k_gemm1,   dim3(16, 160, BB), dim3(256), 0, stream, m_in, q_in, pw);
    hipLaunchKernelGGL(k_argmax,  dim3(10240),       dim3(256), 0, stream, pw, centers);
    hipLaunchKernelGGL(k_colstats,dim3(4, NCH, BB),  dim3(256), 0, stream, pw, centers, part);
    hipLaunchKernelGGL(k_reduce,  dim3(16),          dim3(256), 0, stream, part, stats);
    hipLaunchKernelGGL(k_pw,      dim3(THW, BB),     dim3(256), 0, stream, pw, centers, stats);
    hipLaunchKernelGGL(k_gemm2,   dim3(8, 8, 16),    dim3(256), 0, stream, m_out, pw, out);
}

// Round 3
// 613.677 us; speedup vs baseline: 1.8573x; 1.8573x over previous
//
#include <hip/hip_runtime.h>
#include <hip/hip_bf16.h>

#define BB 4
#define DE 128
#define DO_ 512
#define THW 10240
#define HW 1024
#define SCALE 0.08838834764831845f      // 1/sqrt(128)
#define INV2S2 0.05555555555555555f     // 1/(2*3^2)
#define NCH 32
#define CHT 320                          // 10240 / 32

// ws layout: floats [0, 352256) then bf16 buffers (byte offsets below).
// Total ws requirement: 127,238,144 bytes (~121.3 MiB).
#define WS_CENTERS 0                     // 2 * BB * THW floats
#define WS_PART    81920                 // BB * NCH * HW * 2 floats
#define WS_STATS   344064                // BB * HW * 2 floats
#define WS_MO16_B  1409024ull            // bf16 mo   [B][Do][THW]  (41.94 MB)
#define WS_PWT_B   43352064ull           // bf16 pw^T [B][HW][THW]  (83.89 MB)

using bf16x8 = __attribute__((ext_vector_type(8))) short;
using f32x4  = __attribute__((ext_vector_type(4))) float;
using u16x8  = __attribute__((ext_vector_type(8))) unsigned short;

__device__ __forceinline__ unsigned short f2bf(float f) {
    __hip_bfloat16 h = __float2bfloat16(f);
    return *reinterpret_cast<unsigned short*>(&h);
}
__device__ __forceinline__ void glds16(const void* g, void* l) {
    __builtin_amdgcn_global_load_lds((const __attribute__((address_space(1))) void*)g,
                                     (__attribute__((address_space(3))) void*)l,
                                     16, 0, 0);
}

// ---------------- init: zero mem part of out, copy q_out part ----------------
__global__ __launch_bounds__(256) void k_init(float* __restrict__ out,
                                              const float* __restrict__ qout)
{
    int idx = blockIdx.x * 256 + threadIdx.x;
    int b  = idx >> 18;
    int r  = idx & 262143;
    int c  = r >> 8;
    int q4 = r & 255;
    float4* dst = (float4*)out + idx;
    if (c < DO_) {
        *dst = make_float4(0.f, 0.f, 0.f, 0.f);
    } else {
        const float4* src = (const float4*)qout + ((size_t)(b * DO_ + (c - DO_)) << 8) + q4;
        *dst = *src;
    }
}

// ---------------- GEMM1: p[b][t][q] = sum_k mi[b][k][t] * qi[b][k][q] * SCALE ----------------
__global__ __launch_bounds__(256) void k_gemm1(const float* __restrict__ mi,
                                               const float* __restrict__ qi,
                                               float* __restrict__ p)
{
    __shared__ float As[DE][64];
    __shared__ float Bs[DE][64];
    int qb = blockIdx.x, tb = blockIdx.y, b = blockIdx.z;
    int tid = threadIdx.x;
    const float* A  = mi + (size_t)b * DE * THW + tb * 64;
    const float* Bq = qi + (size_t)b * DE * HW + qb * 64;
#pragma unroll
    for (int i = 0; i < 8; ++i) {
        int s = tid + i * 256;
        int k = s >> 4, c4 = (s & 15) << 2;
        *(float4*)&As[k][c4] = *(const float4*)&A[(size_t)k * THW + c4];
        *(float4*)&Bs[k][c4] = *(const float4*)&Bq[(size_t)k * HW + c4];
    }
    __syncthreads();
    int tx = tid & 15, ty = tid >> 4;
    float acc[4][4] = {};
#pragma unroll 8
    for (int k = 0; k < DE; ++k) {
        float4 a  = *(float4*)&As[k][ty << 2];
        float4 bq = *(float4*)&Bs[k][tx << 2];
        float av[4] = {a.x, a.y, a.z, a.w};
        float bv[4] = {bq.x, bq.y, bq.z, bq.w};
#pragma unroll
        for (int i = 0; i < 4; ++i)
#pragma unroll
            for (int j = 0; j < 4; ++j)
                acc[i][j] = fmaf(av[i], bv[j], acc[i][j]);
    }
    float* pp = p + ((size_t)b * THW + tb * 64 + (ty << 2)) * HW + qb * 64 + (tx << 2);
#pragma unroll
    for (int i = 0; i < 4; ++i) {
        float4 v = make_float4(acc[i][0] * SCALE, acc[i][1] * SCALE,
                               acc[i][2] * SCALE, acc[i][3] * SCALE);
        *(float4*)&pp[(size_t)i * HW] = v;
    }
}

// ---------------- argmax over q per (b,t) row; store gaussian center (cx, cy) ----------------
__global__ __launch_bounds__(256) void k_argmax(const float* __restrict__ p,
                                                float* __restrict__ centers)
{
    int row  = blockIdx.x * 4 + (threadIdx.x >> 6);
    int lane = threadIdx.x & 63;
    const float4* pr = (const float4*)(p + (size_t)row * HW);
    float best = -3.4e38f; int bi = 0;
#pragma unroll
    for (int j = 0; j < 4; ++j) {
        float4 v = pr[j * 64 + lane];
        int base = j * 256 + lane * 4;
        if (v.x > best) { best = v.x; bi = base; }
        if (v.y > best) { best = v.y; bi = base + 1; }
        if (v.z > best) { best = v.z; bi = base + 2; }
        if (v.w > best) { best = v.w; bi = base + 3; }
    }
    for (int off = 1; off < 64; off <<= 1) {
        float ov = __shfl_xor(best, off);
        int   oi = __shfl_xor(bi, off);
        if (ov > best || (ov == best && oi < bi)) { best = ov; bi = oi; }
    }
    if (lane == 0) {
        centers[(size_t)row * 2]     = (float)(bi & 31);   // cx
        centers[(size_t)row * 2 + 1] = (float)(bi >> 5);   // cy
    }
}

// ---------------- online softmax stats over t (chunked): z = p - d2*INV2S2 ----------------
__global__ __launch_bounds__(256) void k_colstats(const float* __restrict__ p,
                                                  const float* __restrict__ centers,
                                                  float* __restrict__ part)
{
    int q  = blockIdx.x * 256 + threadIdx.x;
    int ch = blockIdx.y, b = blockIdx.z;
    float x = (float)(q & 31), y = (float)(q >> 5);
    const float* pp = p + ((size_t)b * THW + ch * CHT) * HW + q;
    const float2* ctr = (const float2*)centers + (size_t)b * THW + ch * CHT;
    float m = -3.0e38f, s = 0.f;
    for (int i = 0; i < CHT; ++i) {
        float2 c = ctr[i];
        float dx = x - c.x, dy = y - c.y;
        float z = pp[(size_t)i * HW] - (dx * dx + dy * dy) * INV2S2;
        float nm = fmaxf(m, z);
        s = s * __expf(m - nm) + __expf(z - nm);
        m = nm;
    }
    size_t o = ((size_t)(b * NCH + ch) * HW + q) * 2;
    part[o] = m; part[o + 1] = s;
}

// ---------------- combine chunk partials -> (M, 1/S) per (b,q) ----------------
__global__ __launch_bounds__(256) void k_reduce(const float* __restrict__ part,
                                                float* __restrict__ stats)
{
    int i = blockIdx.x * 256 + threadIdx.x;
    int b = i >> 10, q = i & 1023;
    float M = -3.0e38f;
#pragma unroll
    for (int c = 0; c < NCH; ++c)
        M = fmaxf(M, part[((size_t)(b * NCH + c) * HW + q) * 2]);
    float S = 0.f;
#pragma unroll
    for (int c = 0; c < NCH; ++c) {
        size_t o = ((size_t)(b * NCH + c) * HW + q) * 2;
        S += part[o + 1] * __expf(part[o] - M);
    }
    stats[(size_t)i * 2] = M;
    stats[(size_t)i * 2 + 1] = 1.0f / S;
}

// ---------------- p_w fp32 (in place) + bf16 transposed copy pwT[b][q][t] ----------------
__global__ __launch_bounds__(256) void k_pwt(float* __restrict__ p,
                                             const float* __restrict__ centers,
                                             const float* __restrict__ stats,
                                             unsigned short* __restrict__ pwT)
{
    __shared__ float tile[64][65];
    __shared__ float ctr[128];    // 64 x (cx, cy)
    __shared__ float st[128];     // 64 x (M, invS)
    int qb = blockIdx.x, tb = blockIdx.y, b = blockIdx.z;
    int tid = threadIdx.x;
    if (tid < 128) {
        ctr[tid] = centers[((size_t)b * THW + tb * 64) * 2 + tid];
        st[tid]  = stats[((size_t)b * HW + qb * 64) * 2 + tid];
    }
    __syncthreads();
    // phase A: pw = exp(p - d2*INV2S2 - M) * invS; write fp32, stash in LDS
    int r0 = tid >> 4;
    int c4 = (tid & 15) << 2;
#pragma unroll
    for (int i = 0; i < 4; ++i) {
        int r = r0 + i * 16;                       // t-local
        float* pp = p + ((size_t)b * THW + tb * 64 + r) * HW + qb * 64 + c4;
        float4 v = *(float4*)pp;
        float cx = ctr[r * 2], cy = ctr[r * 2 + 1];
        float vv[4] = {v.x, v.y, v.z, v.w};
#pragma unroll
        for (int j = 0; j < 4; ++j) {
            int q = qb * 64 + c4 + j;
            float x = (float)(q & 31), y = (float)(q >> 5);
            float dx = x - cx, dy = y - cy;
            vv[j] = __expf(vv[j] - (dx * dx + dy * dy) * INV2S2 - st[(c4 + j) * 2])
                    * st[(c4 + j) * 2 + 1];
            tile[r][c4 + j] = vv[j];
        }
        *(float4*)pp = make_float4(vv[0], vv[1], vv[2], vv[3]);
    }
    __syncthreads();
    // phase B: transposed bf16 write (row = q-local, 64 t contiguous)
    int ql = tid >> 3;
    int t0 = (tid & 7) << 3;
#pragma unroll
    for (int pass = 0; pass < 2; ++pass) {
        int q = ql + pass * 32;
        u16x8 o8;
#pragma unroll
        for (int j = 0; j < 8; ++j)
            o8[j] = f2bf(tile[t0 + j][q]);
        *(u16x8*)&pwT[((size_t)b * HW + qb * 64 + q) * THW + tb * 64 + t0] = o8;
    }
}

// ---------------- mo fp32 -> bf16 ----------------
__global__ __launch_bounds__(256) void k_mo16(const float* __restrict__ mo,
                                              unsigned short* __restrict__ o)
{
    size_t base = ((size_t)blockIdx.x * 256 + threadIdx.x) * 8;
    float4 a = *(const float4*)(mo + base);
    float4 c = *(const float4*)(mo + base + 4);
    u16x8 v;
    v[0] = f2bf(a.x); v[1] = f2bf(a.y); v[2] = f2bf(a.z); v[3] = f2bf(a.w);
    v[4] = f2bf(c.x); v[5] = f2bf(c.y); v[6] = f2bf(c.z); v[7] = f2bf(c.w);
    *(u16x8*)(o + base) = v;
}

// ---------------- GEMM2 (MFMA bf16): mem[b][d][q] += sum_t mo16[b][d][t]*pwT[b][q][t] ----------------
// 128x128 tile, BK=32, 4-way K-split (atomics), global_load_lds staging with
// XOR(k-group, row&3) swizzle. 16x mfma_f32_16x16x32_bf16 + 8x ds_read_b128/iter.
__global__ __launch_bounds__(256) void k_gemm2m(const unsigned short* __restrict__ A16,
                                                const unsigned short* __restrict__ B16,
                                                float* __restrict__ out)
{
    __shared__ unsigned short As[4096];   // [128][32] bf16; 16B-group g at slot g^(row&3)
    __shared__ unsigned short Bs[4096];
    int nb = blockIdx.x, mb = blockIdx.y;
    int b = blockIdx.z >> 2, ks = blockIdx.z & 3;
    int tid = threadIdx.x;
    int w = tid >> 6, lane = tid & 63;
    int quad = lane >> 4, l15 = lane & 15;

    const char* Ag = (const char*)(A16 + (size_t)b * DO_ * THW + (size_t)mb * 128 * THW + ks * 2560);
    const char* Bg = (const char*)(B16 + (size_t)b * HW * THW + (size_t)nb * 128 * THW + ks * 2560);

    int srow = lane >> 2;                    // row within 16-row staging chunk
    int sj   = (lane & 3) ^ (srow & 3);      // swizzled k-group this lane fetches
    const char* aP0 = Ag + (size_t)((w * 2 + 0) * 16 + srow) * (THW * 2) + sj * 16;
    const char* aP1 = Ag + (size_t)((w * 2 + 1) * 16 + srow) * (THW * 2) + sj * 16;
    const char* bP0 = Bg + (size_t)((w * 2 + 0) * 16 + srow) * (THW * 2) + sj * 16;
    const char* bP1 = Bg + (size_t)((w * 2 + 1) * 16 + srow) * (THW * 2) + sj * 16;
    char* lA0 = (char*)As + (w * 2 + 0) * 1024;
    char* lA1 = (char*)As + (w * 2 + 1) * 1024;
    char* lB0 = (char*)Bs + (w * 2 + 0) * 1024;
    char* lB1 = (char*)Bs + (w * 2 + 1) * 1024;

    int wm = w >> 1, wn = w & 1;
    int fq = ((l15 & 3) ^ quad) << 4;        // swizzled frag k-group offset
    const char* aF = (const char*)As + (wm * 64 + l15) * 64 + fq;
    const char* bF = (const char*)Bs + (wn * 64 + l15) * 64 + fq;

    f32x4 acc[4][4];
#pragma unroll
    for (int i = 0; i < 4; ++i)
#pragma unroll
        for (int j = 0; j < 4; ++j)
            acc[i][j] = (f32x4){0.f, 0.f, 0.f, 0.f};

    for (int kit = 0; kit < 80; ++kit) {
        int kb = kit * 64;
        __syncthreads();
        glds16(aP0 + kb, lA0);
        glds16(aP1 + kb, lA1);
        glds16(bP0 + kb, lB0);
        glds16(bP1 + kb, lB1);
        __syncthreads();
        bf16x8 af[4], bfr[4];
#pragma unroll
        for (int i = 0; i < 4; ++i) af[i]  = *(const bf16x8*)(aF + i * 1024);
#pragma unroll
        for (int j = 0; j < 4; ++j) bfr[j] = *(const bf16x8*)(bF + j * 1024);
#pragma unroll
        for (int i = 0; i < 4; ++i)
#pragma unroll
            for (int j = 0; j < 4; ++j)
                acc[i][j] = __builtin_amdgcn_mfma_f32_16x16x32_bf16(af[i], bfr[j], acc[i][j], 0, 0, 0);
    }

    float* Cg = out + (size_t)b * (2 * DO_ * HW);
    int d0 = mb * 128 + wm * 64 + quad * 4;
    int q0 = nb * 128 + wn * 64 + l15;
#pragma unroll
    for (int i = 0; i < 4; ++i)
#pragma unroll
        for (int j = 0; j < 4; ++j)
#pragma unroll
            for (int r = 0; r < 4; ++r)
                atomicAdd(&Cg[(size_t)(d0 + i * 16 + r) * HW + q0 + j * 16], acc[i][j][r]);
}

extern "C" void kernel_launch(void* const* d_in, const int* in_sizes, int n_in,
                              void* d_out, int out_size, void* d_ws, size_t ws_size,
                              hipStream_t stream)
{
    const float* m_in  = (const float*)d_in[0];
    const float* m_out = (const float*)d_in[1];
    const float* q_in  = (const float*)d_in[2];
    const float* q_out = (const float*)d_in[3];
    float* out = (float*)d_out;
    float* pw  = out + (size_t)BB * 2 * DO_ * HW;   // p / p_w region of d_out (in place)
    float* ws  = (float*)d_ws;
    float* centers = ws + WS_CENTERS;
    float* part    = ws + WS_PART;
    float* stats   = ws + WS_STATS;
    unsigned short* mo16  = (unsigned short*)((char*)d_ws + WS_MO16_B);
    unsigned short* pwT16 = (unsigned short*)((char*)d_ws + WS_PWT_B);

    hipLaunchKernelGGL(k_init,    dim3(4096),        dim3(256), 0, stream, out, q_out);
    hipLaunchKernelGGL(k_gemm1,   dim3(16, 160, BB), dim3(256), 0, stream, m_in, q_in, pw);
    hipLaunchKernelGGL(k_argmax,  dim3(10240),       dim3(256), 0, stream, pw, centers);
    hipLaunchKernelGGL(k_colstats,dim3(4, NCH, BB),  dim3(256), 0, stream, pw, centers, part);
    hipLaunchKernelGGL(k_reduce,  dim3(16),          dim3(256), 0, stream, part, stats);
    hipLaunchKernelGGL(k_pwt,     dim3(16, 160, BB), dim3(256), 0, stream, pw, centers, stats, pwT16);
    hipLaunchKernelGGL(k_mo16,    dim3(10240),       dim3(256), 0, stream, m_out, mo16);
    hipLaunchKernelGGL(k_gemm2m,  dim3(8, 4, 16),    dim3(256), 0, stream, mo16, pwT16, out);
}